// Round 20
// baseline (559.060 us; speedup 1.0000x reference)
//
#include <hip/hip_runtime.h>
#include <hip/hip_bf16.h>

#define NN 10000     // nodes
#define NE 100000    // edges
#define DD 64        // node_out_feats
#define EH_ 128      // edge_hidden_feats
#define NI_ 74       // node_in_feats
#define EI_ 12       // edge_in_feats
#define NSTEPS 6
#define PADN 10240
#define GCAP 16384   // max groups (ceil-sum bound 15625)
#define EPB 64       // edges per block in k_eh_s

// Gpk region offsets (ushort elements)
#define RZ_OFF 0          // 8 ct x 4 q
#define NI_OFF 16384      // 4 ct x 2 q
#define NH_OFF 20480
#define WL_OFF 24576
#define BE_OFF 28672
#define G_TOT  32768

typedef short bf16x8 __attribute__((ext_vector_type(8)));
typedef float f32x4 __attribute__((ext_vector_type(4)));

static __device__ __forceinline__ unsigned short f2b(float f) {
    unsigned int u = __float_as_uint(f);
    u += 0x7fffu + ((u >> 16) & 1u);
    return (unsigned short)(u >> 16);
}

__global__ void k_zero(float* p, int n) {
    int i = blockIdx.x * blockDim.x + threadIdx.x;
    if (i < n) p[i] = 0.f;
}

// node_feats = relu(x @ W_proj^T + b_proj); hidden = node_feats; hidb = bf16(hid).
__global__ void k_proj(const float* __restrict__ x, const float* __restrict__ Wp,
                       const float* __restrict__ bp, float* __restrict__ nf,
                       float* __restrict__ hid, unsigned short* __restrict__ hidb) {
    int w = (blockIdx.x * blockDim.x + threadIdx.x) >> 6;
    int lane = threadIdx.x & 63;
    if (w >= PADN) return;
    if (w >= NN) { hidb[(size_t)w * DD + lane] = 0; return; }
    const float* xr = x + (size_t)w * NI_;
    float x0 = xr[lane];
    float x1 = (lane < NI_ - 64) ? xr[64 + lane] : 0.f;
    float acc = bp[lane];
    const float* wr = Wp + (size_t)lane * NI_;
    #pragma unroll
    for (int i = 0; i < 64; i++) acc += __shfl(x0, i, 64) * wr[i];
    #pragma unroll
    for (int i = 0; i < NI_ - 64; i++) acc += __shfl(x1, i, 64) * wr[64 + i];
    acc = fmaxf(acc, 0.f);
    nf[(size_t)w * DD + lane] = acc;
    hid[(size_t)w * DD + lane] = acc;
    hidb[(size_t)w * DD + lane] = f2b(acc);
}

// merged degree kernels: hist[src]++, histd[dst]++
__global__ void k_degs(const int* __restrict__ srcv, const int* __restrict__ dstv,
                       int* __restrict__ hist, int* __restrict__ histd) {
    int e = blockIdx.x * blockDim.x + threadIdx.x;
    if (e < NE) {
        atomicAdd(&hist[srcv[e]], 1);
        atomicAdd(&histd[dstv[e]], 1);
    }
}

// merged: scan hist -> rowptr/cursor; group-list build; scan histd -> rowptrd/cursord.
// Single block 1024 thr.
__global__ void k_scangrp(const int* __restrict__ hist, const int* __restrict__ histd,
                          int* __restrict__ rowptr, int* __restrict__ cursor,
                          int* __restrict__ g_src, int* __restrict__ g_base,
                          int* __restrict__ g_cnt, int* __restrict__ d_ng,
                          int* __restrict__ rowptrd, int* __restrict__ cursord) {
    __shared__ int part[1024];
    int t = threadIdx.x;
    const int PER = (NN + 1023) / 1024;
    int b0 = t * PER;
    // ---- phase 1: src edge-count scan -> rowptr, cursor ----
    int sum = 0;
    for (int i = 0; i < PER; i++) { int b = b0 + i; if (b < NN) sum += hist[b]; }
    part[t] = sum;
    __syncthreads();
    for (int off = 1; off < 1024; off <<= 1) {
        int v = (t >= off) ? part[t - off] : 0;
        __syncthreads();
        part[t] += v;
        __syncthreads();
    }
    int run = (t > 0) ? part[t - 1] : 0;
    for (int i = 0; i <= PER; i++) {
        int b = b0 + i;
        if (b <= NN) {
            rowptr[b] = run;
            if (b < NN) cursor[b] = run;
        }
        if (b < NN && i < PER) run += hist[b];
        if (i == PER) break;
    }
    __syncthreads();
    // ---- phase 2: group-count scan + emit ----
    int cg = 0;
    for (int i = 0; i < PER; i++) {
        int b = b0 + i;
        if (b < NN) cg += (hist[b] + 15) >> 4;
    }
    part[t] = cg;
    __syncthreads();
    for (int off = 1; off < 1024; off <<= 1) {
        int v = (t >= off) ? part[t - off] : 0;
        __syncthreads();
        part[t] += v;
        __syncthreads();
    }
    int grun = (t > 0) ? part[t - 1] : 0;
    for (int i = 0; i < PER; i++) {
        int b = b0 + i;
        if (b >= NN) break;
        int r0 = rowptr[b], r1 = rowptr[b + 1];
        for (int p = r0; p < r1; p += 16) {
            g_src[grun] = b;
            g_base[grun] = p;
            int c = r1 - p; if (c > 16) c = 16;
            g_cnt[grun] = c;
            grun++;
        }
    }
    if (t == 1023) *d_ng = grun;
    __syncthreads();
    // ---- phase 3: dst edge-count scan -> rowptrd, cursord ----
    int sumd = 0;
    for (int i = 0; i < PER; i++) { int b = b0 + i; if (b < NN) sumd += histd[b]; }
    part[t] = sumd;
    __syncthreads();
    for (int off = 1; off < 1024; off <<= 1) {
        int v = (t >= off) ? part[t - off] : 0;
        __syncthreads();
        part[t] += v;
        __syncthreads();
    }
    int rund = (t > 0) ? part[t - 1] : 0;
    for (int i = 0; i <= PER; i++) {
        int b = b0 + i;
        if (b <= NN) {
            rowptrd[b] = rund;
            if (b < NN) cursord[b] = rund;
        }
        if (b < NN && i < PER) rund += histd[b];
        if (i == PER) break;
    }
}

// scatter: perm[src_pos] = e; s2d[src_pos] = dst_pos.
__global__ void k_scatter(const int* __restrict__ srcv, const int* __restrict__ dstv,
                          int* __restrict__ cursor, int* __restrict__ cursord,
                          int* __restrict__ perm, int* __restrict__ s2d) {
    int e = blockIdx.x * blockDim.x + threadIdx.x;
    if (e >= NE) return;
    int s = srcv[e];
    int d = dstv[e];
    int pos = atomicAdd(&cursor[s], 1);
    perm[pos] = e;
    int posd = atomicAdd(&cursord[d], 1);
    s2d[pos] = posd;
}

// eh (sorted order, bf16) = relu(edge_attr[perm[p]] @ W_e1^T + b_e1). 64 edges/block.
__global__ void k_eh_s(const float* __restrict__ ea, const float* __restrict__ W1,
                       const float* __restrict__ b1, const int* __restrict__ perm,
                       unsigned short* __restrict__ ehs) {
    __shared__ float s_W[EH_ * EI_];
    __shared__ float s_b[EH_];
    __shared__ float s_ea[EPB][EI_];
    __shared__ int s_perm[EPB];
    int t = threadIdx.x;
    int p0 = blockIdx.x * EPB;
    for (int i = t; i < EH_ * EI_; i += 256) s_W[i] = W1[i];
    if (t < EH_) s_b[t] = b1[t];
    if (t < EPB) s_perm[t] = (p0 + t < NE) ? perm[p0 + t] : 0;
    __syncthreads();
    for (int i = t; i < EPB * EI_; i += 256) {
        int pl = i / EI_, ii = i % EI_;
        s_ea[pl][ii] = (p0 + pl < NE) ? ea[(size_t)s_perm[pl] * EI_ + ii] : 0.f;
    }
    int le = t >> 7;
    int h = t & 127;
    float wrow[EI_];
    #pragma unroll
    for (int i = 0; i < EI_; i++) wrow[i] = s_W[h * EI_ + i];
    float bb = s_b[h];
    __syncthreads();
    for (int pl = le; pl < EPB; pl += 2) {
        int p = p0 + pl;
        if (p >= NE) break;
        float acc = bb;
        #pragma unroll
        for (int i = 0; i < EI_; i++) acc += s_ea[pl][i] * wrow[i];
        ehs[(size_t)p * EH_ + h] = f2b(fmaxf(acc, 0.f));
    }
}

// Pack W_e2 into bf16 MFMA A-fragment order for k_fv (verified R9).
__global__ void k_pA(const float* __restrict__ W2, unsigned short* __restrict__ Apk) {
    int idx = blockIdx.x * 256 + threadIdx.x;
    if (idx >= (1 << 19)) return;
    int j = idx & 7;
    int n = (idx >> 3) & 15;
    int g = (idx >> 7) & 3;
    int frag = (idx >> 9) & 1;
    int f = (idx >> 10) & 63;
    int hB = (idx >> 16) & 1;
    int ks = idx >> 17;
    int d = frag * 32 + g * 8 + j;
    int h = ks * 32 + hB * 16 + n;
    Apk[idx] = f2b(W2[((size_t)(d * 64 + f)) * EH_ + h]);
}

// Pack GRU/xp weights into MFMA B-fragment order.
__global__ void k_pG(const float* __restrict__ Wih, const float* __restrict__ Whh,
                     const float* __restrict__ Wl, const float* __restrict__ be2,
                     unsigned short* __restrict__ Gpk) {
    int idx = blockIdx.x * 256 + threadIdx.x;
    if (idx >= G_TOT) return;
    int j = idx & 7, n = (idx >> 3) & 15, g = (idx >> 7) & 3;
    float v;
    if (idx < NI_OFF) {                       // rz: nq=4, K=128, c in [0,128)
        int rem = idx >> 9;
        int q = rem & 3, ct = rem >> 2;
        int c = ct * 16 + n, k = q * 32 + g * 8 + j;
        v = (k < 64) ? Wih[(size_t)c * 64 + k] : Whh[(size_t)c * 64 + (k - 64)];
    } else if (idx < NH_OFF) {                // i_n: nq=2
        int l = idx - NI_OFF; int rem = l >> 9;
        int q = rem & 1, ct = rem >> 1;
        int c = ct * 16 + n, k = q * 32 + g * 8 + j;
        v = Wih[(size_t)(128 + c) * 64 + k];
    } else if (idx < WL_OFF) {                // h_n
        int l = idx - NH_OFF; int rem = l >> 9;
        int q = rem & 1, ct = rem >> 1;
        int c = ct * 16 + n, k = q * 32 + g * 8 + j;
        v = Whh[(size_t)(128 + c) * 64 + k];
    } else if (idx < BE_OFF) {                // Wl
        int l = idx - WL_OFF; int rem = l >> 9;
        int q = rem & 1, ct = rem >> 1;
        int c = ct * 16 + n, k = q * 32 + g * 8 + j;
        v = Wl[(size_t)c * 64 + k];
    } else {                                  // be2 reshaped [d][f]
        int l = idx - BE_OFF; int rem = l >> 9;
        int q = rem & 1, ct = rem >> 1;
        int c = ct * 16 + n, k = q * 32 + g * 8 + j;
        v = be2[(size_t)k * 64 + c];
    }
    Gpk[idx] = f2b(v);
}

__global__ void k_tr64(const float* __restrict__ W, float* __restrict__ Wt) {
    int idx = blockIdx.x * 256 + threadIdx.x;
    if (idx >= 64 * 64) return;
    int r = idx >> 6, c = idx & 63;
    Wt[c * 64 + r] = W[idx];
}

// per-step gather (vectorized): msg rows for node are CONTIGUOUS
// [rowptrd[node], rowptrd[node+1]). One wave per node; 4 lane-groups of 16
// each take every 4th row with f32x4 loads; combine via shfl_xor(16,32).
__global__ void k_prep(const float* __restrict__ msg, const int* __restrict__ rowptrd,
                       unsigned short* __restrict__ nfvb) {
    int node = (blockIdx.x * blockDim.x + threadIdx.x) >> 6;
    int lane = threadIdx.x & 63;
    int q = lane >> 4, m = lane & 15;
    if (node >= PADN) return;
    unsigned long long* outp = (unsigned long long*)(nfvb + (size_t)node * DD) + m;
    if (node >= NN) { if (q == 0) *outp = 0ULL; return; }
    int r0 = rowptrd[node], r1 = rowptrd[node + 1];
    f32x4 acc = {0.f, 0.f, 0.f, 0.f};
    for (int p = r0 + q; p < r1; p += 4) {
        f32x4 v = *(const f32x4*)(msg + (size_t)p * DD + m * 4);
        acc += v;
    }
    acc[0] += __shfl_xor(acc[0], 16, 64);
    acc[1] += __shfl_xor(acc[1], 16, 64);
    acc[2] += __shfl_xor(acc[2], 16, 64);
    acc[3] += __shfl_xor(acc[3], 16, 64);
    acc[0] += __shfl_xor(acc[0], 32, 64);
    acc[1] += __shfl_xor(acc[1], 32, 64);
    acc[2] += __shfl_xor(acc[2], 32, 64);
    acc[3] += __shfl_xor(acc[3], 32, 64);
    if (q == 0) {
        float inv = 1.f / fmaxf((float)(r1 - r0), 1.f);
        unsigned long long r =
              (unsigned long long)f2b(fmaxf(acc[0] * inv, 0.f))
            | ((unsigned long long)f2b(fmaxf(acc[1] * inv, 0.f)) << 16)
            | ((unsigned long long)f2b(fmaxf(acc[2] * inv, 0.f)) << 32)
            | ((unsigned long long)f2b(fmaxf(acc[3] * inv, 0.f)) << 48);
        *outp = r;
    }
}

// Initial xp = nf @ Wl^T + bl (-> xpb); btp = xp @ be2. VALU, once.
__global__ void k_xp(const float* __restrict__ nf, const float* __restrict__ WlT,
                     const float* __restrict__ bl, const float* __restrict__ be2,
                     unsigned short* __restrict__ xpb, float* __restrict__ btp) {
    int wid = (blockIdx.x * blockDim.x + threadIdx.x) >> 6;
    int lane = threadIdx.x & 63;
    int s0 = wid * 4;
    if (s0 >= NN) return;
    int nv = (NN - s0 < 4) ? (NN - s0) : 4;
    float nvv[4], acc[4], bt[4];
    float blv = bl[lane];
    #pragma unroll
    for (int i = 0; i < 4; i++) {
        int s = s0 + (i < nv ? i : nv - 1);
        nvv[i] = nf[(size_t)s * DD + lane];
        acc[i] = blv;
        bt[i] = 0.f;
    }
    for (int d = 0; d < 64; d++) {
        float wv = WlT[d * 64 + lane];
        #pragma unroll
        for (int i = 0; i < 4; i++)
            acc[i] = fmaf(__shfl(nvv[i], d, 64), wv, acc[i]);
    }
    for (int d = 0; d < 64; d++) {
        float bv = be2[d * 64 + lane];
        #pragma unroll
        for (int i = 0; i < 4; i++)
            bt[i] = fmaf(__shfl(acc[i], d, 64), bv, bt[i]);
    }
    #pragma unroll
    for (int i = 0; i < 4; i++) {
        if (i < nv) {
            xpb[(size_t)(s0 + i) * DD + lane] = f2b(acc[i]);
            btp[(size_t)(s0 + i) * DD + lane] = bt[i];
        }
    }
}

// Fused V-GEMM + edge MFMA. Block = 16 waves (1024 thr), 16 groups. (verified R9
// compute; epilogue now stages rows in the wave's own dead LDS region and writes
// each msg row as one contiguous 256B burst -- no partial-line scatter.)
__global__ __launch_bounds__(1024, 8) void k_fv(
        const unsigned short* __restrict__ xpb,
        const unsigned short* __restrict__ Apk,
        const int* __restrict__ g_src, const int* __restrict__ g_base,
        const int* __restrict__ g_cnt, const int* __restrict__ d_ng,
        const unsigned short* __restrict__ ehs, const int* __restrict__ s2d,
        const float* __restrict__ btp, float* __restrict__ msg) {
    __shared__ unsigned char lds[66560];   // 64KB V-slices + 1KB dst indices
    int ng = *d_ng;
    int nb = blockIdx.x * 16;
    if (nb >= ng) return;
    int tid = threadIdx.x;
    int w = tid >> 6, lane = tid & 63;
    int g = lane >> 4, n = lane & 15;

    int srcn = g_src[nb + n];
    const unsigned short* xr = xpb + (size_t)srcn * DD + g * 8;
    bf16x8 xb0 = *(const bf16x8*)xr;
    bf16x8 xb1 = *(const bf16x8*)(xr + 32);

    int gi = nb + w;
    int sq = g_src[gi], bq = g_base[gi], cq = g_cnt[gi];

    f32x4 acc[4];
    #pragma unroll
    for (int nt = 0; nt < 4; nt++) {
        f32x4 z = {0.f, 0.f, 0.f, 0.f};
        acc[nt] = z;
    }

    for (int ks = 0; ks < 4; ks++) {
        if (ks) __syncthreads();
        #pragma unroll
        for (int hB = 0; hB < 2; hB++) {
            int ho = hB * 2 + (g >> 1);
            int hq0 = (g & 1) * 4;
            int abase = (n << 12) | (ho << 4) | (hq0 << 1);
            const unsigned short* apks =
                Apk + (size_t)((ks * 2 + hB) * 64 + (w << 2)) * 1024 + g * 128 + n * 8;
            #pragma unroll
            for (int fi = 0; fi < 4; fi++) {
                int f = (w << 2) + fi;
                const unsigned short* ap = apks + fi * 1024;
                bf16x8 A0 = *(const bf16x8*)ap;
                bf16x8 A1 = *(const bf16x8*)(ap + 512);
                f32x4 d = {0.f, 0.f, 0.f, 0.f};
                __builtin_amdgcn_s_setprio(1);
                d = __builtin_amdgcn_mfma_f32_16x16x32_bf16(A0, xb0, d, 0, 0, 0);
                d = __builtin_amdgcn_mfma_f32_16x16x32_bf16(A1, xb1, d, 0, 0, 0);
                __builtin_amdgcn_s_setprio(0);
                unsigned int lo = (unsigned)f2b(d[0]) | ((unsigned)f2b(d[1]) << 16);
                unsigned int hi = (unsigned)f2b(d[2]) | ((unsigned)f2b(d[3]) << 16);
                int addr = abase | (f << 6);
                addr ^= ((n ^ f) & 7) << 4;
                *(unsigned long long*)(lds + addr) =
                    (unsigned long long)lo | ((unsigned long long)hi << 32);
            }
        }
        bf16x8 aeh = *(const bf16x8*)(ehs + (size_t)(bq + n) * EH_ + ks * 32 + g * 8);
        __syncthreads();
        bf16x8 Bf[4];
        #pragma unroll
        for (int nt = 0; nt < 4; nt++) {
            int f = nt * 16 + n;
            int addr = (w << 12) | (f << 6) | (g << 4);
            addr ^= ((w ^ f) & 7) << 4;
            Bf[nt] = *(const bf16x8*)(lds + addr);
        }
        __builtin_amdgcn_s_setprio(1);
        #pragma unroll
        for (int nt = 0; nt < 4; nt++)
            acc[nt] = __builtin_amdgcn_mfma_f32_16x16x32_bf16(aeh, Bf[nt], acc[nt], 0, 0, 0);
        __builtin_amdgcn_s_setprio(0);
    }
    if (cq == 0) return;
    // ---- epilogue: wave-synchronous stage into own (dead) 4KB LDS region,
    // then coalesced 256B row writes. No barrier needed: after the last
    // __syncthreads, region w is read only by wave w (phase-B addressing).
    int dpr[4];
    #pragma unroll
    for (int rg = 0; rg < 4; rg++) {
        int m = g * 4 + rg;
        dpr[rg] = (m < cq) ? s2d[bq + m] : -1;
    }
    float* sf = (float*)lds + (size_t)w * 1024;
    int* ldsI = (int*)(lds + 65536) + w * 16;
    #pragma unroll
    for (int nt = 0; nt < 4; nt++) {
        float btv = btp[(size_t)sq * DD + nt * 16 + n];
        int col = (nt * 16 + n) ^ (g << 4);    // bank swizzle: <=2-way
        #pragma unroll
        for (int rg = 0; rg < 4; rg++)
            sf[(g * 4 + rg) * 64 + col] = acc[nt][rg] + btv;
    }
    if (n == 0) {
        #pragma unroll
        for (int rg = 0; rg < 4; rg++) ldsI[g * 4 + rg] = dpr[rg];
    }
    #pragma unroll
    for (int p = 0; p < 4; p++) {
        int r = p * 4 + (lane >> 4);           // row 0..15; r>>2 == p
        int dstrow = ldsI[r];
        if (dstrow >= 0) {
            int c4 = (lane & 15) * 4;
            f32x4 v = *(const f32x4*)&sf[r * 64 + (c4 ^ (p << 4))];
            *(f32x4*)(msg + (size_t)dstrow * DD + c4) = v;
        }
    }
}

// MFMA GRU + xp + btp. Block = 4 waves, 64 nodes (4 m-tiles of 16). (verified R12)
__global__ void k_gx(const unsigned short* __restrict__ nfvb,
                     const unsigned short* __restrict__ hidb,
                     const float* __restrict__ hid,
                     const unsigned short* __restrict__ Gpk,
                     const float* __restrict__ bih, const float* __restrict__ bhh,
                     const float* __restrict__ bl,
                     float* __restrict__ out_nf, unsigned short* __restrict__ xpb,
                     float* __restrict__ btp, int doXp) {
    __shared__ unsigned short s_nf[64 * 64];
    __shared__ unsigned short s_xp[64 * 64];
    int tid = threadIdx.x;
    int w = tid >> 6, lane = tid & 63;
    int g = lane >> 4, n = lane & 15;
    int nb = blockIdx.x * 64;
    int jj = w * 16 + n;

    bf16x8 Br[4], Bz[4], Bi[2], Bh[2], Bw[2], Be[2];
    #pragma unroll
    for (int q = 0; q < 4; q++) {
        Br[q] = *(const bf16x8*)(Gpk + RZ_OFF + (size_t)(((w) * 4 + q) * 4 + g) * 128 + n * 8);
        Bz[q] = *(const bf16x8*)(Gpk + RZ_OFF + (size_t)(((w + 4) * 4 + q) * 4 + g) * 128 + n * 8);
    }
    #pragma unroll
    for (int q = 0; q < 2; q++) {
        Bi[q] = *(const bf16x8*)(Gpk + NI_OFF + (size_t)((w * 2 + q) * 4 + g) * 128 + n * 8);
        Bh[q] = *(const bf16x8*)(Gpk + NH_OFF + (size_t)((w * 2 + q) * 4 + g) * 128 + n * 8);
        Bw[q] = *(const bf16x8*)(Gpk + WL_OFF + (size_t)((w * 2 + q) * 4 + g) * 128 + n * 8);
        Be[q] = *(const bf16x8*)(Gpk + BE_OFF + (size_t)((w * 2 + q) * 4 + g) * 128 + n * 8);
    }
    float br_ = bih[jj] + bhh[jj];
    float bz_ = bih[64 + jj] + bhh[64 + jj];
    float bi_ = bih[128 + jj];
    float bh_ = bhh[128 + jj];
    float blv = bl[jj];

    #pragma unroll
    for (int mt = 0; mt < 4; mt++) {
        int arow = nb + mt * 16 + n;
        const unsigned short* na = nfvb + (size_t)arow * DD + g * 8;
        const unsigned short* ha = hidb + (size_t)arow * DD + g * 8;
        bf16x8 A0 = *(const bf16x8*)na, A1 = *(const bf16x8*)(na + 32);
        bf16x8 H0 = *(const bf16x8*)ha, H1 = *(const bf16x8*)(ha + 32);
        f32x4 aR = {0.f, 0.f, 0.f, 0.f}, aZ = aR, aI = aR, aH = aR;
        __builtin_amdgcn_s_setprio(1);
        aR = __builtin_amdgcn_mfma_f32_16x16x32_bf16(A0, Br[0], aR, 0, 0, 0);
        aR = __builtin_amdgcn_mfma_f32_16x16x32_bf16(A1, Br[1], aR, 0, 0, 0);
        aR = __builtin_amdgcn_mfma_f32_16x16x32_bf16(H0, Br[2], aR, 0, 0, 0);
        aR = __builtin_amdgcn_mfma_f32_16x16x32_bf16(H1, Br[3], aR, 0, 0, 0);
        aZ = __builtin_amdgcn_mfma_f32_16x16x32_bf16(A0, Bz[0], aZ, 0, 0, 0);
        aZ = __builtin_amdgcn_mfma_f32_16x16x32_bf16(A1, Bz[1], aZ, 0, 0, 0);
        aZ = __builtin_amdgcn_mfma_f32_16x16x32_bf16(H0, Bz[2], aZ, 0, 0, 0);
        aZ = __builtin_amdgcn_mfma_f32_16x16x32_bf16(H1, Bz[3], aZ, 0, 0, 0);
        aI = __builtin_amdgcn_mfma_f32_16x16x32_bf16(A0, Bi[0], aI, 0, 0, 0);
        aI = __builtin_amdgcn_mfma_f32_16x16x32_bf16(A1, Bi[1], aI, 0, 0, 0);
        aH = __builtin_amdgcn_mfma_f32_16x16x32_bf16(H0, Bh[0], aH, 0, 0, 0);
        aH = __builtin_amdgcn_mfma_f32_16x16x32_bf16(H1, Bh[1], aH, 0, 0, 0);
        __builtin_amdgcn_s_setprio(0);
        #pragma unroll
        for (int rg = 0; rg < 4; rg++) {
            int row = mt * 16 + g * 4 + rg;
            int node = nb + row;
            float r = 1.f / (1.f + __expf(-(aR[rg] + br_)));
            float z = 1.f / (1.f + __expf(-(aZ[rg] + bz_)));
            float nn2 = tanhf(aI[rg] + bi_ + r * (aH[rg] + bh_));
            float hv = (node < NN) ? hid[(size_t)node * DD + jj] : 0.f;
            float nf_ = (1.f - z) * nn2 + z * hv;
            if (node < NN) out_nf[(size_t)node * DD + jj] = nf_;
            int ba = (row * 128 + jj * 2) ^ ((row & 7) << 4);
            s_nf[ba >> 1] = f2b(nf_);
        }
    }
    if (!doXp) return;
    __syncthreads();
    #pragma unroll
    for (int mt = 0; mt < 4; mt++) {
        int row = mt * 16 + n;
        int sw = (row & 7) << 4;
        bf16x8 X0 = *(const bf16x8*)((const unsigned char*)s_nf + ((row * 128 + g * 16) ^ sw));
        bf16x8 X1 = *(const bf16x8*)((const unsigned char*)s_nf + ((row * 128 + 64 + g * 16) ^ sw));
        f32x4 aX = {0.f, 0.f, 0.f, 0.f};
        aX = __builtin_amdgcn_mfma_f32_16x16x32_bf16(X0, Bw[0], aX, 0, 0, 0);
        aX = __builtin_amdgcn_mfma_f32_16x16x32_bf16(X1, Bw[1], aX, 0, 0, 0);
        #pragma unroll
        for (int rg = 0; rg < 4; rg++) {
            int row2 = mt * 16 + g * 4 + rg;
            int ba = (row2 * 128 + jj * 2) ^ ((row2 & 7) << 4);
            s_xp[ba >> 1] = f2b(aX[rg] + blv);
        }
    }
    __syncthreads();
    {
        int row = w * 16 + n;
        int sw = (row & 7) << 4;
        #pragma unroll
        for (int h2 = 0; h2 < 2; h2++) {
            int byteo = (row * 128 + (h2 * 4 + g) * 16) ^ sw;
            bf16x8 v = *(const bf16x8*)((const unsigned char*)s_xp + byteo);
            *(bf16x8*)(xpb + (size_t)(nb + row) * DD + (h2 * 4 + g) * 8) = v;
        }
    }
    #pragma unroll
    for (int mt = 0; mt < 4; mt++) {
        int row = mt * 16 + n;
        int sw = (row & 7) << 4;
        bf16x8 X0 = *(const bf16x8*)((const unsigned char*)s_xp + ((row * 128 + g * 16) ^ sw));
        bf16x8 X1 = *(const bf16x8*)((const unsigned char*)s_xp + ((row * 128 + 64 + g * 16) ^ sw));
        f32x4 aB = {0.f, 0.f, 0.f, 0.f};
        aB = __builtin_amdgcn_mfma_f32_16x16x32_bf16(X0, Be[0], aB, 0, 0, 0);
        aB = __builtin_amdgcn_mfma_f32_16x16x32_bf16(X1, Be[1], aB, 0, 0, 0);
        #pragma unroll
        for (int rg = 0; rg < 4; rg++) {
            int node = nb + mt * 16 + g * 4 + rg;
            if (node < NN) btp[(size_t)node * DD + jj] = aB[rg];
        }
    }
}

extern "C" void kernel_launch(void* const* d_in, const int* in_sizes, int n_in,
                              void* d_out, int out_size, void* d_ws, size_t ws_size,
                              hipStream_t stream) {
    const float* x   = (const float*)d_in[0];
    const int*   ei  = (const int*)d_in[1];
    const float* ea  = (const float*)d_in[2];
    const float* Wp  = (const float*)d_in[3];
    const float* bp  = (const float*)d_in[4];
    const float* W1  = (const float*)d_in[5];
    const float* b1  = (const float*)d_in[6];
    const float* W2  = (const float*)d_in[7];
    const float* b2  = (const float*)d_in[8];
    const float* Wl  = (const float*)d_in[9];
    const float* bl  = (const float*)d_in[10];
    const float* Wih = (const float*)d_in[11];
    const float* Whh = (const float*)d_in[12];
    const float* bih = (const float*)d_in[13];
    const float* bhh = (const float*)d_in[14];
    const int* srcv = ei;
    const int* dstv = ei + NE;

    float* p = (float*)d_ws;
    size_t off = 0;
    auto alloc = [&](size_t n) { n = (n + 3) & ~(size_t)3; float* q = p + off; off += n; return q; };
    float* nf   = alloc((size_t)NN * DD);
    float* hid  = alloc((size_t)NN * DD);
    float* btp  = alloc((size_t)NN * DD);
    unsigned short* ehs = (unsigned short*)alloc((size_t)(NE + 16) * EH_ / 2);  // bf16
    float* WlT  = alloc(64 * 64);
    int* hist   = (int*)alloc(NN);     // hist/histd contiguous (zeroed together)
    int* histd  = (int*)alloc(NN);
    int* rowptr = (int*)alloc(NN + 1);
    int* cursor = (int*)alloc(NN);
    int* rowptrd = (int*)alloc(NN + 1);
    int* cursord = (int*)alloc(NN);
    int* perm   = (int*)alloc(NE);
    int* s2d    = (int*)alloc(NE);
    int* g_src  = (int*)alloc(GCAP);   // g_src/g_base/g_cnt contiguous
    int* g_base = (int*)alloc(GCAP);
    int* g_cnt  = (int*)alloc(GCAP);
    int* d_ng   = (int*)alloc(4);
    unsigned short* Apk  = (unsigned short*)alloc((size_t)(1 << 19) / 2);      // bf16, 1MB
    unsigned short* Gpk  = (unsigned short*)alloc((size_t)G_TOT / 2);          // bf16, 64KB
    unsigned short* xpb  = (unsigned short*)alloc((size_t)PADN * DD / 2);      // bf16
    unsigned short* nfvb = (unsigned short*)alloc((size_t)PADN * DD / 2);      // bf16
    unsigned short* hidb = (unsigned short*)alloc((size_t)PADN * DD / 2);      // bf16
    float* msg = alloc((size_t)NE * DD);                                       // 25.6MB

    // ---- one-time preprocessing ----
    k_zero<<<(2 * NN + 255) / 256, 256, 0, stream>>>((float*)hist, 2 * NN);
    k_zero<<<(3 * GCAP + 255) / 256, 256, 0, stream>>>((float*)g_src, 3 * GCAP);
    k_proj<<<(PADN + 3) / 4, 256, 0, stream>>>(x, Wp, bp, nf, hid, hidb);
    k_pA<<<(1 << 19) / 256, 256, 0, stream>>>(W2, Apk);
    k_pG<<<(G_TOT + 255) / 256, 256, 0, stream>>>(Wih, Whh, Wl, b2, Gpk);
    k_tr64<<<16, 256, 0, stream>>>(Wl, WlT);
    k_degs<<<(NE + 255) / 256, 256, 0, stream>>>(srcv, dstv, hist, histd);
    k_scangrp<<<1, 1024, 0, stream>>>(hist, histd, rowptr, cursor,
                                      g_src, g_base, g_cnt, d_ng, rowptrd, cursord);
    k_scatter<<<(NE + 255) / 256, 256, 0, stream>>>(srcv, dstv, cursor, cursord,
                                                    perm, s2d);
    k_eh_s<<<(NE + EPB - 1) / EPB, 256, 0, stream>>>(ea, W1, b1, perm, ehs);

    const int nw_quarter = (NN + 3) / 4;
    const int gx_blocks = (NN + 63) / 64;
    const int prep_blocks = PADN / 4;   // one wave per node
    k_xp<<<(nw_quarter + 3) / 4, 256, 0, stream>>>(nf, WlT, bl, b2, xpb, btp);
    for (int s = 0; s < NSTEPS; s++) {
        k_fv<<<GCAP / 16, 1024, 0, stream>>>(xpb, Apk, g_src, g_base, g_cnt, d_ng,
                                             ehs, s2d, btp, msg);
        k_prep<<<prep_blocks, 256, 0, stream>>>(msg, rowptrd, nfvb);
        float* dest = (s == NSTEPS - 1) ? (float*)d_out : nf;
        k_gx<<<gx_blocks, 256, 0, stream>>>(nfvb, hidb, hid, Gpk, bih, bhh, bl,
                                            dest, xpb, btp,
                                            (s < NSTEPS - 1) ? 1 : 0);
    }
}

// Round 21
// 550.500 us; speedup vs baseline: 1.0155x; 1.0155x over previous
//
#include <hip/hip_runtime.h>
#include <hip/hip_bf16.h>

#define NN 10000     // nodes
#define NE 100000    // edges
#define DD 64        // node_out_feats
#define EH_ 128      // edge_hidden_feats
#define NI_ 74       // node_in_feats
#define EI_ 12       // edge_in_feats
#define NSTEPS 6
#define PADN 10240
#define GCAP 16384   // max groups (ceil-sum bound 15625)
#define EPB 64       // edges per block in k_eh_s

// Gpk region offsets (ushort elements)
#define RZ_OFF 0          // 8 ct x 4 q
#define NI_OFF 16384      // 4 ct x 2 q
#define NH_OFF 20480
#define WL_OFF 24576
#define BE_OFF 28672
#define G_TOT  32768

typedef short bf16x8 __attribute__((ext_vector_type(8)));
typedef float f32x4 __attribute__((ext_vector_type(4)));

static __device__ __forceinline__ unsigned short f2b(float f) {
    unsigned int u = __float_as_uint(f);
    u += 0x7fffu + ((u >> 16) & 1u);
    return (unsigned short)(u >> 16);
}

__global__ void k_zero(float* p, int n) {
    int i = blockIdx.x * blockDim.x + threadIdx.x;
    if (i < n) p[i] = 0.f;
}

// node_feats = relu(x @ W_proj^T + b_proj); hidden = node_feats; hidb = bf16(hid).
__global__ void k_proj(const float* __restrict__ x, const float* __restrict__ Wp,
                       const float* __restrict__ bp, float* __restrict__ nf,
                       float* __restrict__ hid, unsigned short* __restrict__ hidb) {
    int w = (blockIdx.x * blockDim.x + threadIdx.x) >> 6;
    int lane = threadIdx.x & 63;
    if (w >= PADN) return;
    if (w >= NN) { hidb[(size_t)w * DD + lane] = 0; return; }
    const float* xr = x + (size_t)w * NI_;
    float x0 = xr[lane];
    float x1 = (lane < NI_ - 64) ? xr[64 + lane] : 0.f;
    float acc = bp[lane];
    const float* wr = Wp + (size_t)lane * NI_;
    #pragma unroll
    for (int i = 0; i < 64; i++) acc += __shfl(x0, i, 64) * wr[i];
    #pragma unroll
    for (int i = 0; i < NI_ - 64; i++) acc += __shfl(x1, i, 64) * wr[64 + i];
    acc = fmaxf(acc, 0.f);
    nf[(size_t)w * DD + lane] = acc;
    hid[(size_t)w * DD + lane] = acc;
    hidb[(size_t)w * DD + lane] = f2b(acc);
}

// merged degree kernels: hist[src]++, histd[dst]++
__global__ void k_degs(const int* __restrict__ srcv, const int* __restrict__ dstv,
                       int* __restrict__ hist, int* __restrict__ histd) {
    int e = blockIdx.x * blockDim.x + threadIdx.x;
    if (e < NE) {
        atomicAdd(&hist[srcv[e]], 1);
        atomicAdd(&histd[dstv[e]], 1);
    }
}

// merged: scan hist -> rowptr/cursor; group-list build; scan histd -> rowptrd/cursord.
// Single block 1024 thr.
__global__ void k_scangrp(const int* __restrict__ hist, const int* __restrict__ histd,
                          int* __restrict__ rowptr, int* __restrict__ cursor,
                          int* __restrict__ g_src, int* __restrict__ g_base,
                          int* __restrict__ g_cnt, int* __restrict__ d_ng,
                          int* __restrict__ rowptrd, int* __restrict__ cursord) {
    __shared__ int part[1024];
    int t = threadIdx.x;
    const int PER = (NN + 1023) / 1024;
    int b0 = t * PER;
    // ---- phase 1: src edge-count scan -> rowptr, cursor ----
    int sum = 0;
    for (int i = 0; i < PER; i++) { int b = b0 + i; if (b < NN) sum += hist[b]; }
    part[t] = sum;
    __syncthreads();
    for (int off = 1; off < 1024; off <<= 1) {
        int v = (t >= off) ? part[t - off] : 0;
        __syncthreads();
        part[t] += v;
        __syncthreads();
    }
    int run = (t > 0) ? part[t - 1] : 0;
    for (int i = 0; i <= PER; i++) {
        int b = b0 + i;
        if (b <= NN) {
            rowptr[b] = run;
            if (b < NN) cursor[b] = run;
        }
        if (b < NN && i < PER) run += hist[b];
        if (i == PER) break;
    }
    __syncthreads();
    // ---- phase 2: group-count scan + emit ----
    int cg = 0;
    for (int i = 0; i < PER; i++) {
        int b = b0 + i;
        if (b < NN) cg += (hist[b] + 15) >> 4;
    }
    part[t] = cg;
    __syncthreads();
    for (int off = 1; off < 1024; off <<= 1) {
        int v = (t >= off) ? part[t - off] : 0;
        __syncthreads();
        part[t] += v;
        __syncthreads();
    }
    int grun = (t > 0) ? part[t - 1] : 0;
    for (int i = 0; i < PER; i++) {
        int b = b0 + i;
        if (b >= NN) break;
        int r0 = rowptr[b], r1 = rowptr[b + 1];
        for (int p = r0; p < r1; p += 16) {
            g_src[grun] = b;
            g_base[grun] = p;
            int c = r1 - p; if (c > 16) c = 16;
            g_cnt[grun] = c;
            grun++;
        }
    }
    if (t == 1023) *d_ng = grun;
    __syncthreads();
    // ---- phase 3: dst edge-count scan -> rowptrd, cursord ----
    int sumd = 0;
    for (int i = 0; i < PER; i++) { int b = b0 + i; if (b < NN) sumd += histd[b]; }
    part[t] = sumd;
    __syncthreads();
    for (int off = 1; off < 1024; off <<= 1) {
        int v = (t >= off) ? part[t - off] : 0;
        __syncthreads();
        part[t] += v;
        __syncthreads();
    }
    int rund = (t > 0) ? part[t - 1] : 0;
    for (int i = 0; i <= PER; i++) {
        int b = b0 + i;
        if (b <= NN) {
            rowptrd[b] = rund;
            if (b < NN) cursord[b] = rund;
        }
        if (b < NN && i < PER) rund += histd[b];
        if (i == PER) break;
    }
}

// scatter: perm[src_pos] = e; s2d[src_pos] = dst_pos.
__global__ void k_scatter(const int* __restrict__ srcv, const int* __restrict__ dstv,
                          int* __restrict__ cursor, int* __restrict__ cursord,
                          int* __restrict__ perm, int* __restrict__ s2d) {
    int e = blockIdx.x * blockDim.x + threadIdx.x;
    if (e >= NE) return;
    int s = srcv[e];
    int d = dstv[e];
    int pos = atomicAdd(&cursor[s], 1);
    perm[pos] = e;
    int posd = atomicAdd(&cursord[d], 1);
    s2d[pos] = posd;
}

// eh (sorted order, bf16) = relu(edge_attr[perm[p]] @ W_e1^T + b_e1). 64 edges/block.
__global__ void k_eh_s(const float* __restrict__ ea, const float* __restrict__ W1,
                       const float* __restrict__ b1, const int* __restrict__ perm,
                       unsigned short* __restrict__ ehs) {
    __shared__ float s_W[EH_ * EI_];
    __shared__ float s_b[EH_];
    __shared__ float s_ea[EPB][EI_];
    __shared__ int s_perm[EPB];
    int t = threadIdx.x;
    int p0 = blockIdx.x * EPB;
    for (int i = t; i < EH_ * EI_; i += 256) s_W[i] = W1[i];
    if (t < EH_) s_b[t] = b1[t];
    if (t < EPB) s_perm[t] = (p0 + t < NE) ? perm[p0 + t] : 0;
    __syncthreads();
    for (int i = t; i < EPB * EI_; i += 256) {
        int pl = i / EI_, ii = i % EI_;
        s_ea[pl][ii] = (p0 + pl < NE) ? ea[(size_t)s_perm[pl] * EI_ + ii] : 0.f;
    }
    int le = t >> 7;
    int h = t & 127;
    float wrow[EI_];
    #pragma unroll
    for (int i = 0; i < EI_; i++) wrow[i] = s_W[h * EI_ + i];
    float bb = s_b[h];
    __syncthreads();
    for (int pl = le; pl < EPB; pl += 2) {
        int p = p0 + pl;
        if (p >= NE) break;
        float acc = bb;
        #pragma unroll
        for (int i = 0; i < EI_; i++) acc += s_ea[pl][i] * wrow[i];
        ehs[(size_t)p * EH_ + h] = f2b(fmaxf(acc, 0.f));
    }
}

// Pack W_e2 into bf16 MFMA A-fragment order for k_fv (verified R9).
__global__ void k_pA(const float* __restrict__ W2, unsigned short* __restrict__ Apk) {
    int idx = blockIdx.x * 256 + threadIdx.x;
    if (idx >= (1 << 19)) return;
    int j = idx & 7;
    int n = (idx >> 3) & 15;
    int g = (idx >> 7) & 3;
    int frag = (idx >> 9) & 1;
    int f = (idx >> 10) & 63;
    int hB = (idx >> 16) & 1;
    int ks = idx >> 17;
    int d = frag * 32 + g * 8 + j;
    int h = ks * 32 + hB * 16 + n;
    Apk[idx] = f2b(W2[((size_t)(d * 64 + f)) * EH_ + h]);
}

// Pack GRU/xp weights into MFMA B-fragment order.
__global__ void k_pG(const float* __restrict__ Wih, const float* __restrict__ Whh,
                     const float* __restrict__ Wl, const float* __restrict__ be2,
                     unsigned short* __restrict__ Gpk) {
    int idx = blockIdx.x * 256 + threadIdx.x;
    if (idx >= G_TOT) return;
    int j = idx & 7, n = (idx >> 3) & 15, g = (idx >> 7) & 3;
    float v;
    if (idx < NI_OFF) {                       // rz: nq=4, K=128, c in [0,128)
        int rem = idx >> 9;
        int q = rem & 3, ct = rem >> 2;
        int c = ct * 16 + n, k = q * 32 + g * 8 + j;
        v = (k < 64) ? Wih[(size_t)c * 64 + k] : Whh[(size_t)c * 64 + (k - 64)];
    } else if (idx < NH_OFF) {                // i_n: nq=2
        int l = idx - NI_OFF; int rem = l >> 9;
        int q = rem & 1, ct = rem >> 1;
        int c = ct * 16 + n, k = q * 32 + g * 8 + j;
        v = Wih[(size_t)(128 + c) * 64 + k];
    } else if (idx < WL_OFF) {                // h_n
        int l = idx - NH_OFF; int rem = l >> 9;
        int q = rem & 1, ct = rem >> 1;
        int c = ct * 16 + n, k = q * 32 + g * 8 + j;
        v = Whh[(size_t)(128 + c) * 64 + k];
    } else if (idx < BE_OFF) {                // Wl
        int l = idx - WL_OFF; int rem = l >> 9;
        int q = rem & 1, ct = rem >> 1;
        int c = ct * 16 + n, k = q * 32 + g * 8 + j;
        v = Wl[(size_t)c * 64 + k];
    } else {                                  // be2 reshaped [d][f]
        int l = idx - BE_OFF; int rem = l >> 9;
        int q = rem & 1, ct = rem >> 1;
        int c = ct * 16 + n, k = q * 32 + g * 8 + j;
        v = be2[(size_t)k * 64 + c];
    }
    Gpk[idx] = f2b(v);
}

__global__ void k_tr64(const float* __restrict__ W, float* __restrict__ Wt) {
    int idx = blockIdx.x * 256 + threadIdx.x;
    if (idx >= 64 * 64) return;
    int r = idx >> 6, c = idx & 63;
    Wt[c * 64 + r] = W[idx];
}

// per-step gather (vectorized): msg rows for node are CONTIGUOUS
// [rowptrd[node], rowptrd[node+1]). One wave per node; 4 lane-groups of 16
// each take every 4th row with f32x4 loads; combine via shfl_xor(16,32).
__global__ void k_prep(const float* __restrict__ msg, const int* __restrict__ rowptrd,
                       unsigned short* __restrict__ nfvb) {
    int node = (blockIdx.x * blockDim.x + threadIdx.x) >> 6;
    int lane = threadIdx.x & 63;
    int q = lane >> 4, m = lane & 15;
    if (node >= PADN) return;
    unsigned long long* outp = (unsigned long long*)(nfvb + (size_t)node * DD) + m;
    if (node >= NN) { if (q == 0) *outp = 0ULL; return; }
    int r0 = rowptrd[node], r1 = rowptrd[node + 1];
    f32x4 acc = {0.f, 0.f, 0.f, 0.f};
    for (int p = r0 + q; p < r1; p += 4) {
        f32x4 v = *(const f32x4*)(msg + (size_t)p * DD + m * 4);
        acc += v;
    }
    acc[0] += __shfl_xor(acc[0], 16, 64);
    acc[1] += __shfl_xor(acc[1], 16, 64);
    acc[2] += __shfl_xor(acc[2], 16, 64);
    acc[3] += __shfl_xor(acc[3], 16, 64);
    acc[0] += __shfl_xor(acc[0], 32, 64);
    acc[1] += __shfl_xor(acc[1], 32, 64);
    acc[2] += __shfl_xor(acc[2], 32, 64);
    acc[3] += __shfl_xor(acc[3], 32, 64);
    if (q == 0) {
        float inv = 1.f / fmaxf((float)(r1 - r0), 1.f);
        unsigned long long r =
              (unsigned long long)f2b(fmaxf(acc[0] * inv, 0.f))
            | ((unsigned long long)f2b(fmaxf(acc[1] * inv, 0.f)) << 16)
            | ((unsigned long long)f2b(fmaxf(acc[2] * inv, 0.f)) << 32)
            | ((unsigned long long)f2b(fmaxf(acc[3] * inv, 0.f)) << 48);
        *outp = r;
    }
}

// Initial xp = nf @ Wl^T + bl (-> xpb); btp = xp @ be2. VALU, once.
__global__ void k_xp(const float* __restrict__ nf, const float* __restrict__ WlT,
                     const float* __restrict__ bl, const float* __restrict__ be2,
                     unsigned short* __restrict__ xpb, float* __restrict__ btp) {
    int wid = (blockIdx.x * blockDim.x + threadIdx.x) >> 6;
    int lane = threadIdx.x & 63;
    int s0 = wid * 4;
    if (s0 >= NN) return;
    int nv = (NN - s0 < 4) ? (NN - s0) : 4;
    float nvv[4], acc[4], bt[4];
    float blv = bl[lane];
    #pragma unroll
    for (int i = 0; i < 4; i++) {
        int s = s0 + (i < nv ? i : nv - 1);
        nvv[i] = nf[(size_t)s * DD + lane];
        acc[i] = blv;
        bt[i] = 0.f;
    }
    for (int d = 0; d < 64; d++) {
        float wv = WlT[d * 64 + lane];
        #pragma unroll
        for (int i = 0; i < 4; i++)
            acc[i] = fmaf(__shfl(nvv[i], d, 64), wv, acc[i]);
    }
    for (int d = 0; d < 64; d++) {
        float bv = be2[d * 64 + lane];
        #pragma unroll
        for (int i = 0; i < 4; i++)
            bt[i] = fmaf(__shfl(acc[i], d, 64), bv, bt[i]);
    }
    #pragma unroll
    for (int i = 0; i < 4; i++) {
        if (i < nv) {
            xpb[(size_t)(s0 + i) * DD + lane] = f2b(acc[i]);
            btp[(size_t)(s0 + i) * DD + lane] = bt[i];
        }
    }
}

// Fused V-GEMM + edge MFMA. Block = 16 waves (1024 thr), 16 groups. (verified R9
// compute; scatter epilogue verified R16; T5 s_setprio verified R18.)
__global__ __launch_bounds__(1024, 8) void k_fv(
        const unsigned short* __restrict__ xpb,
        const unsigned short* __restrict__ Apk,
        const int* __restrict__ g_src, const int* __restrict__ g_base,
        const int* __restrict__ g_cnt, const int* __restrict__ d_ng,
        const unsigned short* __restrict__ ehs, const int* __restrict__ s2d,
        const float* __restrict__ btp, float* __restrict__ msg) {
    __shared__ unsigned char lds[65536];
    int ng = *d_ng;
    int nb = blockIdx.x * 16;
    if (nb >= ng) return;
    int tid = threadIdx.x;
    int w = tid >> 6, lane = tid & 63;
    int g = lane >> 4, n = lane & 15;

    int srcn = g_src[nb + n];
    const unsigned short* xr = xpb + (size_t)srcn * DD + g * 8;
    bf16x8 xb0 = *(const bf16x8*)xr;
    bf16x8 xb1 = *(const bf16x8*)(xr + 32);

    int gi = nb + w;
    int sq = g_src[gi], bq = g_base[gi], cq = g_cnt[gi];

    f32x4 acc[4];
    #pragma unroll
    for (int nt = 0; nt < 4; nt++) {
        f32x4 z = {0.f, 0.f, 0.f, 0.f};
        acc[nt] = z;
    }

    for (int ks = 0; ks < 4; ks++) {
        if (ks) __syncthreads();
        #pragma unroll
        for (int hB = 0; hB < 2; hB++) {
            int ho = hB * 2 + (g >> 1);
            int hq0 = (g & 1) * 4;
            int abase = (n << 12) | (ho << 4) | (hq0 << 1);
            const unsigned short* apks =
                Apk + (size_t)((ks * 2 + hB) * 64 + (w << 2)) * 1024 + g * 128 + n * 8;
            #pragma unroll
            for (int fi = 0; fi < 4; fi++) {
                int f = (w << 2) + fi;
                const unsigned short* ap = apks + fi * 1024;
                bf16x8 A0 = *(const bf16x8*)ap;
                bf16x8 A1 = *(const bf16x8*)(ap + 512);
                f32x4 d = {0.f, 0.f, 0.f, 0.f};
                __builtin_amdgcn_s_setprio(1);
                d = __builtin_amdgcn_mfma_f32_16x16x32_bf16(A0, xb0, d, 0, 0, 0);
                d = __builtin_amdgcn_mfma_f32_16x16x32_bf16(A1, xb1, d, 0, 0, 0);
                __builtin_amdgcn_s_setprio(0);
                unsigned int lo = (unsigned)f2b(d[0]) | ((unsigned)f2b(d[1]) << 16);
                unsigned int hi = (unsigned)f2b(d[2]) | ((unsigned)f2b(d[3]) << 16);
                int addr = abase | (f << 6);
                addr ^= ((n ^ f) & 7) << 4;
                *(unsigned long long*)(lds + addr) =
                    (unsigned long long)lo | ((unsigned long long)hi << 32);
            }
        }
        bf16x8 aeh = *(const bf16x8*)(ehs + (size_t)(bq + n) * EH_ + ks * 32 + g * 8);
        __syncthreads();
        bf16x8 Bf[4];
        #pragma unroll
        for (int nt = 0; nt < 4; nt++) {
            int f = nt * 16 + n;
            int addr = (w << 12) | (f << 6) | (g << 4);
            addr ^= ((w ^ f) & 7) << 4;
            Bf[nt] = *(const bf16x8*)(lds + addr);
        }
        __builtin_amdgcn_s_setprio(1);
        #pragma unroll
        for (int nt = 0; nt < 4; nt++)
            acc[nt] = __builtin_amdgcn_mfma_f32_16x16x32_bf16(aeh, Bf[nt], acc[nt], 0, 0, 0);
        __builtin_amdgcn_s_setprio(0);
    }
    if (cq == 0) return;
    int dpr[4];
    #pragma unroll
    for (int rg = 0; rg < 4; rg++) {
        int m = g * 4 + rg;
        dpr[rg] = (m < cq) ? s2d[bq + m] : -1;
    }
    #pragma unroll
    for (int nt = 0; nt < 4; nt++) {
        float btv = btp[(size_t)sq * DD + nt * 16 + n];
        #pragma unroll
        for (int rg = 0; rg < 4; rg++) {
            if (dpr[rg] >= 0)
                msg[(size_t)dpr[rg] * DD + nt * 16 + n] = acc[nt][rg] + btv;
        }
    }
}

// MFMA GRU + xp + btp. Block = 4 waves, 64 nodes (4 m-tiles of 16). (verified R12
// + T5 setprio verified R18.)
__global__ void k_gx(const unsigned short* __restrict__ nfvb,
                     const unsigned short* __restrict__ hidb,
                     const float* __restrict__ hid,
                     const unsigned short* __restrict__ Gpk,
                     const float* __restrict__ bih, const float* __restrict__ bhh,
                     const float* __restrict__ bl,
                     float* __restrict__ out_nf, unsigned short* __restrict__ xpb,
                     float* __restrict__ btp, int doXp) {
    __shared__ unsigned short s_nf[64 * 64];
    __shared__ unsigned short s_xp[64 * 64];
    int tid = threadIdx.x;
    int w = tid >> 6, lane = tid & 63;
    int g = lane >> 4, n = lane & 15;
    int nb = blockIdx.x * 64;
    int jj = w * 16 + n;

    bf16x8 Br[4], Bz[4], Bi[2], Bh[2], Bw[2], Be[2];
    #pragma unroll
    for (int q = 0; q < 4; q++) {
        Br[q] = *(const bf16x8*)(Gpk + RZ_OFF + (size_t)(((w) * 4 + q) * 4 + g) * 128 + n * 8);
        Bz[q] = *(const bf16x8*)(Gpk + RZ_OFF + (size_t)(((w + 4) * 4 + q) * 4 + g) * 128 + n * 8);
    }
    #pragma unroll
    for (int q = 0; q < 2; q++) {
        Bi[q] = *(const bf16x8*)(Gpk + NI_OFF + (size_t)((w * 2 + q) * 4 + g) * 128 + n * 8);
        Bh[q] = *(const bf16x8*)(Gpk + NH_OFF + (size_t)((w * 2 + q) * 4 + g) * 128 + n * 8);
        Bw[q] = *(const bf16x8*)(Gpk + WL_OFF + (size_t)((w * 2 + q) * 4 + g) * 128 + n * 8);
        Be[q] = *(const bf16x8*)(Gpk + BE_OFF + (size_t)((w * 2 + q) * 4 + g) * 128 + n * 8);
    }
    float br_ = bih[jj] + bhh[jj];
    float bz_ = bih[64 + jj] + bhh[64 + jj];
    float bi_ = bih[128 + jj];
    float bh_ = bhh[128 + jj];
    float blv = bl[jj];

    #pragma unroll
    for (int mt = 0; mt < 4; mt++) {
        int arow = nb + mt * 16 + n;
        const unsigned short* na = nfvb + (size_t)arow * DD + g * 8;
        const unsigned short* ha = hidb + (size_t)arow * DD + g * 8;
        bf16x8 A0 = *(const bf16x8*)na, A1 = *(const bf16x8*)(na + 32);
        bf16x8 H0 = *(const bf16x8*)ha, H1 = *(const bf16x8*)(ha + 32);
        f32x4 aR = {0.f, 0.f, 0.f, 0.f}, aZ = aR, aI = aR, aH = aR;
        __builtin_amdgcn_s_setprio(1);
        aR = __builtin_amdgcn_mfma_f32_16x16x32_bf16(A0, Br[0], aR, 0, 0, 0);
        aR = __builtin_amdgcn_mfma_f32_16x16x32_bf16(A1, Br[1], aR, 0, 0, 0);
        aR = __builtin_amdgcn_mfma_f32_16x16x32_bf16(H0, Br[2], aR, 0, 0, 0);
        aR = __builtin_amdgcn_mfma_f32_16x16x32_bf16(H1, Br[3], aR, 0, 0, 0);
        aZ = __builtin_amdgcn_mfma_f32_16x16x32_bf16(A0, Bz[0], aZ, 0, 0, 0);
        aZ = __builtin_amdgcn_mfma_f32_16x16x32_bf16(A1, Bz[1], aZ, 0, 0, 0);
        aZ = __builtin_amdgcn_mfma_f32_16x16x32_bf16(H0, Bz[2], aZ, 0, 0, 0);
        aZ = __builtin_amdgcn_mfma_f32_16x16x32_bf16(H1, Bz[3], aZ, 0, 0, 0);
        aI = __builtin_amdgcn_mfma_f32_16x16x32_bf16(A0, Bi[0], aI, 0, 0, 0);
        aI = __builtin_amdgcn_mfma_f32_16x16x32_bf16(A1, Bi[1], aI, 0, 0, 0);
        aH = __builtin_amdgcn_mfma_f32_16x16x32_bf16(H0, Bh[0], aH, 0, 0, 0);
        aH = __builtin_amdgcn_mfma_f32_16x16x32_bf16(H1, Bh[1], aH, 0, 0, 0);
        __builtin_amdgcn_s_setprio(0);
        #pragma unroll
        for (int rg = 0; rg < 4; rg++) {
            int row = mt * 16 + g * 4 + rg;
            int node = nb + row;
            float r = 1.f / (1.f + __expf(-(aR[rg] + br_)));
            float z = 1.f / (1.f + __expf(-(aZ[rg] + bz_)));
            float nn2 = tanhf(aI[rg] + bi_ + r * (aH[rg] + bh_));
            float hv = (node < NN) ? hid[(size_t)node * DD + jj] : 0.f;
            float nf_ = (1.f - z) * nn2 + z * hv;
            if (node < NN) out_nf[(size_t)node * DD + jj] = nf_;
            int ba = (row * 128 + jj * 2) ^ ((row & 7) << 4);
            s_nf[ba >> 1] = f2b(nf_);
        }
    }
    if (!doXp) return;
    __syncthreads();
    #pragma unroll
    for (int mt = 0; mt < 4; mt++) {
        int row = mt * 16 + n;
        int sw = (row & 7) << 4;
        bf16x8 X0 = *(const bf16x8*)((const unsigned char*)s_nf + ((row * 128 + g * 16) ^ sw));
        bf16x8 X1 = *(const bf16x8*)((const unsigned char*)s_nf + ((row * 128 + 64 + g * 16) ^ sw));
        f32x4 aX = {0.f, 0.f, 0.f, 0.f};
        aX = __builtin_amdgcn_mfma_f32_16x16x32_bf16(X0, Bw[0], aX, 0, 0, 0);
        aX = __builtin_amdgcn_mfma_f32_16x16x32_bf16(X1, Bw[1], aX, 0, 0, 0);
        #pragma unroll
        for (int rg = 0; rg < 4; rg++) {
            int row2 = mt * 16 + g * 4 + rg;
            int ba = (row2 * 128 + jj * 2) ^ ((row2 & 7) << 4);
            s_xp[ba >> 1] = f2b(aX[rg] + blv);
        }
    }
    __syncthreads();
    {
        int row = w * 16 + n;
        int sw = (row & 7) << 4;
        #pragma unroll
        for (int h2 = 0; h2 < 2; h2++) {
            int byteo = (row * 128 + (h2 * 4 + g) * 16) ^ sw;
            bf16x8 v = *(const bf16x8*)((const unsigned char*)s_xp + byteo);
            *(bf16x8*)(xpb + (size_t)(nb + row) * DD + (h2 * 4 + g) * 8) = v;
        }
    }
    #pragma unroll
    for (int mt = 0; mt < 4; mt++) {
        int row = mt * 16 + n;
        int sw = (row & 7) << 4;
        bf16x8 X0 = *(const bf16x8*)((const unsigned char*)s_xp + ((row * 128 + g * 16) ^ sw));
        bf16x8 X1 = *(const bf16x8*)((const unsigned char*)s_xp + ((row * 128 + 64 + g * 16) ^ sw));
        f32x4 aB = {0.f, 0.f, 0.f, 0.f};
        aB = __builtin_amdgcn_mfma_f32_16x16x32_bf16(X0, Be[0], aB, 0, 0, 0);
        aB = __builtin_amdgcn_mfma_f32_16x16x32_bf16(X1, Be[1], aB, 0, 0, 0);
        #pragma unroll
        for (int rg = 0; rg < 4; rg++) {
            int node = nb + mt * 16 + g * 4 + rg;
            if (node < NN) btp[(size_t)node * DD + jj] = aB[rg];
        }
    }
}

extern "C" void kernel_launch(void* const* d_in, const int* in_sizes, int n_in,
                              void* d_out, int out_size, void* d_ws, size_t ws_size,
                              hipStream_t stream) {
    const float* x   = (const float*)d_in[0];
    const int*   ei  = (const int*)d_in[1];
    const float* ea  = (const float*)d_in[2];
    const float* Wp  = (const float*)d_in[3];
    const float* bp  = (const float*)d_in[4];
    const float* W1  = (const float*)d_in[5];
    const float* b1  = (const float*)d_in[6];
    const float* W2  = (const float*)d_in[7];
    const float* b2  = (const float*)d_in[8];
    const float* Wl  = (const float*)d_in[9];
    const float* bl  = (const float*)d_in[10];
    const float* Wih = (const float*)d_in[11];
    const float* Whh = (const float*)d_in[12];
    const float* bih = (const float*)d_in[13];
    const float* bhh = (const float*)d_in[14];
    const int* srcv = ei;
    const int* dstv = ei + NE;

    float* p = (float*)d_ws;
    size_t off = 0;
    auto alloc = [&](size_t n) { n = (n + 3) & ~(size_t)3; float* q = p + off; off += n; return q; };
    float* nf   = alloc((size_t)NN * DD);
    float* hid  = alloc((size_t)NN * DD);
    float* btp  = alloc((size_t)NN * DD);
    unsigned short* ehs = (unsigned short*)alloc((size_t)(NE + 16) * EH_ / 2);  // bf16
    float* WlT  = alloc(64 * 64);
    int* hist   = (int*)alloc(NN);     // hist/histd contiguous (zeroed together)
    int* histd  = (int*)alloc(NN);
    int* rowptr = (int*)alloc(NN + 1);
    int* cursor = (int*)alloc(NN);
    int* rowptrd = (int*)alloc(NN + 1);
    int* cursord = (int*)alloc(NN);
    int* perm   = (int*)alloc(NE);
    int* s2d    = (int*)alloc(NE);
    int* g_src  = (int*)alloc(GCAP);   // g_src/g_base/g_cnt contiguous
    int* g_base = (int*)alloc(GCAP);
    int* g_cnt  = (int*)alloc(GCAP);
    int* d_ng   = (int*)alloc(4);
    unsigned short* Apk  = (unsigned short*)alloc((size_t)(1 << 19) / 2);      // bf16, 1MB
    unsigned short* Gpk  = (unsigned short*)alloc((size_t)G_TOT / 2);          // bf16, 64KB
    unsigned short* xpb  = (unsigned short*)alloc((size_t)PADN * DD / 2);      // bf16
    unsigned short* nfvb = (unsigned short*)alloc((size_t)PADN * DD / 2);      // bf16
    unsigned short* hidb = (unsigned short*)alloc((size_t)PADN * DD / 2);      // bf16
    float* msg = alloc((size_t)NE * DD);                                       // 25.6MB

    // ---- one-time preprocessing ----
    k_zero<<<(2 * NN + 255) / 256, 256, 0, stream>>>((float*)hist, 2 * NN);
    k_zero<<<(3 * GCAP + 255) / 256, 256, 0, stream>>>((float*)g_src, 3 * GCAP);
    k_proj<<<(PADN + 3) / 4, 256, 0, stream>>>(x, Wp, bp, nf, hid, hidb);
    k_pA<<<(1 << 19) / 256, 256, 0, stream>>>(W2, Apk);
    k_pG<<<(G_TOT + 255) / 256, 256, 0, stream>>>(Wih, Whh, Wl, b2, Gpk);
    k_tr64<<<16, 256, 0, stream>>>(Wl, WlT);
    k_degs<<<(NE + 255) / 256, 256, 0, stream>>>(srcv, dstv, hist, histd);
    k_scangrp<<<1, 1024, 0, stream>>>(hist, histd, rowptr, cursor,
                                      g_src, g_base, g_cnt, d_ng, rowptrd, cursord);
    k_scatter<<<(NE + 255) / 256, 256, 0, stream>>>(srcv, dstv, cursor, cursord,
                                                    perm, s2d);
    k_eh_s<<<(NE + EPB - 1) / EPB, 256, 0, stream>>>(ea, W1, b1, perm, ehs);

    const int nw_quarter = (NN + 3) / 4;
    const int gx_blocks = (NN + 63) / 64;
    const int prep_blocks = PADN / 4;   // one wave per node
    k_xp<<<(nw_quarter + 3) / 4, 256, 0, stream>>>(nf, WlT, bl, b2, xpb, btp);
    for (int s = 0; s < NSTEPS; s++) {
        k_fv<<<GCAP / 16, 1024, 0, stream>>>(xpb, Apk, g_src, g_base, g_cnt, d_ng,
                                             ehs, s2d, btp, msg);
        k_prep<<<prep_blocks, 256, 0, stream>>>(msg, rowptrd, nfvb);
        float* dest = (s == NSTEPS - 1) ? (float*)d_out : nf;
        k_gx<<<gx_blocks, 256, 0, stream>>>(nfvb, hidb, hid, Gpk, bih, bhh, bl,
                                            dest, xpb, btp,
                                            (s < NSTEPS - 1) ? 1 : 0);
    }
}